// Round 1
// baseline (1351.383 us; speedup 1.0000x reference)
//
#include <hip/hip_runtime.h>
#include <math.h>

namespace {

constexpr int NSMP = 131072;   // n_samples
constexpr int NEV  = 128;      // B*E events
constexpr int MFT  = 262144;   // 2*NS FFT size = 512*512
constexpr int COLS = 8;        // cols per pass A/C block
constexpr int ROWS = 8;        // rows per pass B block

__device__ __forceinline__ float2 cadd(float2 a, float2 b){ return make_float2(a.x+b.x, a.y+b.y); }
__device__ __forceinline__ float2 csub(float2 a, float2 b){ return make_float2(a.x-b.x, a.y-b.y); }
__device__ __forceinline__ float2 cmul(float2 a, float2 b){ return make_float2(a.x*b.x - a.y*b.y, a.x*b.y + a.y*b.x); }
__device__ __forceinline__ float2 cmulc(float2 a, float2 b){ return make_float2(a.x*b.x + a.y*b.y, a.y*b.x - a.x*b.y); }

// 8-point DFT: out[k] = sum_j in[j] * exp(SGN*2*pi*i*j*k/8)
template<int SGN>
__device__ __forceinline__ void fft8v(float2* u) {
  const float S2 = 0.70710678118654752440f;
  float2 a0 = cadd(u[0], u[4]), a1 = csub(u[0], u[4]);
  float2 a2 = cadd(u[2], u[6]), a3 = csub(u[2], u[6]);
  float2 b0 = cadd(u[1], u[5]), b1 = csub(u[1], u[5]);
  float2 b2 = cadd(u[3], u[7]), b3 = csub(u[3], u[7]);
  float2 a3r = (SGN < 0) ? make_float2(a3.y, -a3.x) : make_float2(-a3.y, a3.x);
  float2 b3r = (SGN < 0) ? make_float2(b3.y, -b3.x) : make_float2(-b3.y, b3.x);
  float2 E0 = cadd(a0, a2), E2 = csub(a0, a2);
  float2 E1 = cadd(a1, a3r), E3 = csub(a1, a3r);
  float2 O0 = cadd(b0, b2), O2 = csub(b0, b2);
  float2 O1 = cadd(b1, b3r), O3 = csub(b1, b3r);
  const float sg = (SGN < 0) ? -1.f : 1.f;
  O1 = cmul(O1, make_float2(S2, sg*S2));
  O2 = (SGN < 0) ? make_float2(O2.y, -O2.x) : make_float2(-O2.y, O2.x);
  O3 = cmul(O3, make_float2(-S2, sg*S2));
  u[0] = cadd(E0, O0); u[4] = csub(E0, O0);
  u[1] = cadd(E1, O1); u[5] = csub(E1, O1);
  u[2] = cadd(E2, O2); u[6] = csub(E2, O2);
  u[3] = cadd(E3, O3); u[7] = csub(E3, O3);
}

// In-place 512-pt forward DIF (natural in -> base-8 digit-reversed out).
// Element i lives at X[i*S]. One wave (lane 0..63) per transform.
__device__ void fft512_fwd(float2* X, int S, int lane, const float2* w512) {
  float2 u[8];
  #pragma unroll
  for (int j = 0; j < 8; ++j) u[j] = X[((j<<6) + lane)*S];
  fft8v<-1>(u);
  #pragma unroll
  for (int r = 1; r < 8; ++r) u[r] = cmul(u[r], w512[(lane*r) & 511]);
  #pragma unroll
  for (int r = 0; r < 8; ++r) X[((r<<6) + lane)*S] = u[r];
  __syncthreads();
  {
    int b = (lane>>3)<<6, m = lane&7;
    #pragma unroll
    for (int j = 0; j < 8; ++j) u[j] = X[(b + (j<<3) + m)*S];
    fft8v<-1>(u);
    #pragma unroll
    for (int r = 1; r < 8; ++r) u[r] = cmul(u[r], w512[((m*r)<<3) & 511]);
    #pragma unroll
    for (int r = 0; r < 8; ++r) X[(b + (r<<3) + m)*S] = u[r];
  }
  __syncthreads();
  {
    int c = lane<<3;
    #pragma unroll
    for (int j = 0; j < 8; ++j) u[j] = X[(c + j)*S];
    fft8v<-1>(u);
    #pragma unroll
    for (int r = 0; r < 8; ++r) X[(c + r)*S] = u[r];
  }
  __syncthreads();
}

// In-place 512-pt inverse (transpose-conjugate of fwd): digit-reversed in -> natural out. Unnormalized.
__device__ void fft512_inv(float2* X, int S, int lane, const float2* w512) {
  float2 u[8];
  {
    int c = lane<<3;
    #pragma unroll
    for (int r = 0; r < 8; ++r) u[r] = X[(c + r)*S];
    fft8v<1>(u);
    #pragma unroll
    for (int j = 0; j < 8; ++j) X[(c + j)*S] = u[j];
  }
  __syncthreads();
  {
    int b = (lane>>3)<<6, m = lane&7;
    #pragma unroll
    for (int r = 0; r < 8; ++r) u[r] = X[(b + (r<<3) + m)*S];
    #pragma unroll
    for (int r = 1; r < 8; ++r) u[r] = cmulc(u[r], w512[((m*r)<<3) & 511]);
    fft8v<1>(u);
    #pragma unroll
    for (int j = 0; j < 8; ++j) X[(b + (j<<3) + m)*S] = u[j];
  }
  __syncthreads();
  {
    #pragma unroll
    for (int r = 0; r < 8; ++r) u[r] = X[((r<<6) + lane)*S];
    #pragma unroll
    for (int r = 1; r < 8; ++r) u[r] = cmulc(u[r], w512[(lane*r) & 511]);
    fft8v<1>(u);
    #pragma unroll
    for (int j = 0; j < 8; ++j) X[((j<<6) + lane)*S] = u[j];
  }
  __syncthreads();
}

// -------- per-event scalar params (argmaxes, softmax mix, |amp|) --------
__global__ void k_params(const float* __restrict__ voice, const float* __restrict__ cpc,
                         const float* __restrict__ amps, const float* __restrict__ room,
                         const float* __restrict__ rmix, const float* __restrict__ times,
                         int* __restrict__ vidx, int* __restrict__ cpidx, int* __restrict__ ridx,
                         int* __restrict__ shiftA, float* __restrict__ m0, float* __restrict__ m1,
                         float* __restrict__ amp) {
  int n = blockIdx.x, t = threadIdx.x;
  if (t == 0) {
    const float* p = voice + n*8; int bi = 0; float bv = p[0];
    for (int i = 1; i < 8; ++i) if (p[i] > bv) { bv = p[i]; bi = i; }
    vidx[n] = bi;
  } else if (t == 1) {
    const float* p = cpc + n*512; int bi = 0; float bv = p[0];
    for (int i = 1; i < 512; ++i) if (p[i] > bv) { bv = p[i]; bi = i; }
    cpidx[n] = bi;
  } else if (t == 2) {
    const float* p = room + n*16; int bi = 0; float bv = p[0];
    for (int i = 1; i < 16; ++i) if (p[i] > bv) { bv = p[i]; bi = i; }
    ridx[n] = bi;
  } else if (t == 3) {
    const float* p = times + n*128; int bi = 0; float bv = p[0];
    for (int i = 1; i < 128; ++i) if (p[i] > bv) { bv = p[i]; bi = i; }
    shiftA[n] = bi * 1024;
  } else if (t == 4) {
    float a = rmix[n*2], b = rmix[n*2+1];
    float mx = fmaxf(a, b);
    float ea = __expf(a - mx), eb = __expf(b - mx);
    float inv = 1.f / (ea + eb);
    m0[n] = ea * inv; m1[n] = eb * inv;
    amp[n] = fabsf(amps[n]);
  }
}

// -------- twiddle table W_N^j = exp(-2 pi i j / 262144) --------
__global__ void k_wbig(float2* __restrict__ wbig) {
  int j = blockIdx.x * blockDim.x + threadIdx.x;
  if (j < MFT) {
    double a = -2.0 * 3.14159265358979323846 * (double)j / (double)MFT;
    wbig[j] = make_float2((float)cos(a), (float)sin(a));
  }
}

// -------- M[v] = w_ih[v] @ w_in[v]  -> [8][128][16] --------
__global__ void k_mred(const float* __restrict__ w_ih, const float* __restrict__ w_in,
                       float* __restrict__ mred) {
  int h = blockIdx.x, v = blockIdx.y, t = threadIdx.x;
  const float* ih = w_ih + ((size_t)v*128 + h)*1024;
  const float* wi = w_in + (size_t)v*1024*16;
  float acc[16];
  #pragma unroll
  for (int c = 0; c < 16; ++c) acc[c] = 0.f;
  for (int w = t; w < 1024; w += 64) {
    float a = ih[w];
    const float4* wr = (const float4*)(wi + (size_t)w*16);
    float4 q0 = wr[0], q1 = wr[1], q2 = wr[2], q3 = wr[3];
    acc[0] += a*q0.x; acc[1] += a*q0.y; acc[2] += a*q0.z; acc[3] += a*q0.w;
    acc[4] += a*q1.x; acc[5] += a*q1.y; acc[6] += a*q1.z; acc[7] += a*q1.w;
    acc[8] += a*q2.x; acc[9] += a*q2.y; acc[10]+= a*q2.z; acc[11]+= a*q2.w;
    acc[12]+= a*q3.x; acc[13]+= a*q3.y; acc[14]+= a*q3.z; acc[15]+= a*q3.w;
  }
  #pragma unroll
  for (int c = 0; c < 16; ++c) {
    float s = acc[c];
    for (int o = 32; o > 0; o >>= 1) s += __shfl_down(s, o);
    if (t == 0) mred[((size_t)v*128 + h)*16 + c] = s;
  }
}

// -------- exact top-128 of selected cp_table row (2048 vals), relu, ties by lowest index --------
__global__ __launch_bounds__(256) void k_topk(const float* __restrict__ cp_table,
                                              const int* __restrict__ cpidx,
                                              float* __restrict__ ctrl) {
  __shared__ int redw[4];
  __shared__ int scanbuf[256];
  int n = blockIdx.x, t = threadIdx.x;
  const float* row = cp_table + (size_t)cpidx[n]*2048;
  float f[8]; unsigned v[8];
  #pragma unroll
  for (int i = 0; i < 8; ++i) { f[i] = row[t*8 + i]; v[i] = __float_as_uint(f[i]); }
  int lane = t & 63, wid = t >> 6;
  unsigned thr = 0;
  for (int b = 31; b >= 0; --b) {  // values are >=0, bit pattern is order-preserving
    unsigned cand = thr | (1u << b);
    int c = 0;
    #pragma unroll
    for (int i = 0; i < 8; ++i) c += (v[i] >= cand);
    for (int o = 32; o > 0; o >>= 1) c += __shfl_down(c, o);
    if (lane == 0) redw[wid] = c;
    __syncthreads();
    int tot = redw[0] + redw[1] + redw[2] + redw[3];
    if (tot >= 128) thr = cand;
    __syncthreads();
  }
  int g = 0, eq = 0;
  #pragma unroll
  for (int i = 0; i < 8; ++i) { g += (v[i] > thr); eq += (v[i] == thr); }
  int gw = g;
  for (int o = 32; o > 0; o >>= 1) gw += __shfl_down(gw, o);
  if (lane == 0) redw[wid] = gw;
  scanbuf[t] = eq;
  __syncthreads();
  int G = redw[0] + redw[1] + redw[2] + redw[3];
  int extra = 128 - G;
  int incl = eq;
  for (int o = 1; o < 256; o <<= 1) {
    int add = (t >= o) ? scanbuf[t - o] : 0;
    __syncthreads();
    incl += add;
    scanbuf[t] = incl;
    __syncthreads();
  }
  int rank = incl - eq;
  float* outp = ctrl + (size_t)n*2048;
  #pragma unroll
  for (int i = 0; i < 8; ++i) {
    bool keep = (v[i] > thr) || ((v[i] == thr) && (rank < extra));
    if (v[i] == thr) rank++;
    outp[t*8 + i] = keep ? fmaxf(f[i], 0.f) : 0.f;
  }
}

// -------- 128-step tanh RNN, one block per event, h_i per thread --------
__global__ __launch_bounds__(128) void k_rnn(const float* __restrict__ ctrl,
                                             const float* __restrict__ mred,
                                             const float* __restrict__ w_hh,
                                             const int* __restrict__ vidx,
                                             float* __restrict__ hs) {
  __shared__ __align__(16) float h_s[128];
  __shared__ float ctrl_s[2048];
  int n = blockIdx.x, i = threadIdx.x;
  int v = vidx[n];
  const float4* whhrow = (const float4*)(w_hh + ((size_t)v*128 + i)*128);
  float4 whh[32];
  #pragma unroll
  for (int j = 0; j < 32; ++j) whh[j] = whhrow[j];
  float mr[16];
  const float* mrow = mred + ((size_t)v*128 + i)*16;
  #pragma unroll
  for (int c = 0; c < 16; ++c) mr[c] = mrow[c];
  for (int k = i; k < 2048; k += 128) ctrl_s[k] = ctrl[(size_t)n*2048 + k];
  h_s[i] = 0.f;
  __syncthreads();
  float* hsout = hs + (size_t)n*128*128;
  for (int st = 0; st < 128; ++st) {
    float acc = 0.f;
    #pragma unroll
    for (int c = 0; c < 16; ++c) acc += mr[c] * ctrl_s[(c<<7) + st];
    const float4* hp = (const float4*)h_s;
    #pragma unroll
    for (int j = 0; j < 32; ++j) {
      float4 h4 = hp[j];
      acc += whh[j].x*h4.x + whh[j].y*h4.y + whh[j].z*h4.z + whh[j].w*h4.w;
    }
    float ax = fabsf(acc);
    float e = __expf(2.f*ax);
    float hn = copysignf(1.f - 2.f/(e + 1.f), acc);  // tanh, stable both tails
    __syncthreads();
    h_s[i] = hn;
    hsout[(st<<7) + i] = hn;
    __syncthreads();
  }
}

// -------- sig = sin(hs @ w_out^T), per-event 128x1024 fp32 GEMM --------
__global__ __launch_bounds__(256, 1) void k_gemm(const float* __restrict__ hs,
                                                 const float* __restrict__ w_out,
                                                 const int* __restrict__ vidx,
                                                 float* __restrict__ sig) {
  __shared__ __align__(16) float hs_s[128*36];
  __shared__ __align__(16) float wo_s[128*36];
  int n = blockIdx.y, wt = blockIdx.x, t = threadIdx.x;
  int v = vidx[n];
  const float* hsrc = hs + (size_t)n*128*128;
  const float* wsrc = w_out + ((size_t)v*1024 + wt*128)*128;
  int tx = t & 15, ty = t >> 4;
  int f0 = ty*8, w0 = tx*8;
  float acc[8][8];
  #pragma unroll
  for (int i = 0; i < 8; ++i)
    #pragma unroll
    for (int j = 0; j < 8; ++j) acc[i][j] = 0.f;
  for (int kc = 0; kc < 4; ++kc) {
    for (int i = t; i < 1024; i += 256) {
      int r = i >> 3, q = i & 7;
      ((float4*)(hs_s + r*36))[q] = ((const float4*)(hsrc + r*128 + kc*32))[q];
      ((float4*)(wo_s + r*36))[q] = ((const float4*)(wsrc + r*128 + kc*32))[q];
    }
    __syncthreads();
    #pragma unroll
    for (int h4 = 0; h4 < 8; ++h4) {
      float4 ha[8], wa[8];
      #pragma unroll
      for (int i = 0; i < 8; ++i) ha[i] = *(const float4*)&hs_s[(f0+i)*36 + h4*4];
      #pragma unroll
      for (int j = 0; j < 8; ++j) wa[j] = *(const float4*)&wo_s[(w0+j)*36 + h4*4];
      #pragma unroll
      for (int i = 0; i < 8; ++i)
        #pragma unroll
        for (int j = 0; j < 8; ++j)
          acc[i][j] += ha[i].x*wa[j].x + ha[i].y*wa[j].y + ha[i].z*wa[j].z + ha[i].w*wa[j].w;
    }
    __syncthreads();
  }
  float* dst = sig + (size_t)n*NSMP + wt*128;
  #pragma unroll
  for (int i = 0; i < 8; ++i)
    #pragma unroll
    for (int j = 0; j < 8; ++j)
      dst[(size_t)(f0+i)*1024 + w0 + j] = __sinf(acc[i][j]);
}

// -------- FFT pass A: column FFT-512 over n2 (fused real load + zero-pad) --------
__global__ __launch_bounds__(256) void k_passA(const float* __restrict__ in,
                                               float2* __restrict__ outb,
                                               const float2* __restrict__ wbig) {
  __shared__ float2 w512[512];
  __shared__ float2 tile[512*(COLS+1)];
  int t = threadIdx.x;
  for (int i = t; i < 512; i += 256) w512[i] = wbig[(size_t)i*512];
  const float* src = in + (size_t)blockIdx.y * NSMP;
  float2* dst = outb + (size_t)blockIdx.y * MFT;
  int c0 = blockIdx.x * COLS;
  for (int i = t; i < 512*COLS; i += 256) {
    int cc = i & (COLS-1), n2 = i >> 3;
    float vv = (n2 < 256) ? src[c0 + cc + (n2<<9)] : 0.f;
    tile[n2*(COLS+1) + cc] = make_float2(vv, 0.f);
  }
  __syncthreads();
  int wid = t >> 6, lane = t & 63;
  #pragma unroll
  for (int g = 0; g < COLS/4; ++g)
    fft512_fwd(&tile[(g<<2) + wid], COLS+1, lane, w512);
  for (int i = t; i < 512*COLS; i += 256) {
    int cc = i & (COLS-1), q = i >> 3;
    dst[c0 + cc + (q<<9)] = tile[q*(COLS+1) + cc];
  }
}

// -------- FFT pass B: twiddle + row FFT (+ optional multiply + inverse row FFT + conj twiddle) --------
template<bool MAIN>
__global__ __launch_bounds__(256) void k_passB(float2* __restrict__ Xb,
                                               const float2* __restrict__ spec,
                                               const float2* __restrict__ wbig,
                                               const int* __restrict__ ridx,
                                               const float* __restrict__ m0a,
                                               const float* __restrict__ m1a,
                                               const float* __restrict__ ampa,
                                               int e0) {
  __shared__ float2 w512[512];
  __shared__ float2 rows[ROWS*512];
  int t = threadIdx.x;
  for (int i = t; i < 512; i += 256) w512[i] = wbig[(size_t)i*512];
  float2* Xe = Xb + (size_t)blockIdx.y * MFT;
  int q0 = blockIdx.x * ROWS;
  for (int i = t; i < ROWS*512; i += 256) {
    int r = i >> 9, n1 = i & 511;
    int q = q0 + r;
    int k2 = ((q&7)<<6) | (q&56) | (q>>6);  // base-8 digit reversal of col-FFT position
    rows[i] = cmul(Xe[(size_t)q*512 + n1], wbig[(n1*k2) & (MFT-1)]);
  }
  __syncthreads();
  int wid = t >> 6, lane = t & 63;
  #pragma unroll
  for (int g = 0; g < ROWS/4; ++g)
    fft512_fwd(&rows[((g<<2)+wid)*512], 1, lane, w512);
  if (MAIN) {
    int n = e0 + blockIdx.y;
    int vb = ridx[n];
    float amp = ampa[n];
    float sm0 = amp * m0a[n] * (1.f/(float)MFT);
    float sm1 = amp * m1a[n] * (1.f/(float)MFT);
    const float2* sp = spec + (size_t)vb*MFT + (size_t)q0*512;
    for (int i = t; i < ROWS*512; i += 256) {
      float2 s = sp[i];
      rows[i] = cmul(rows[i], make_float2(sm0*s.x + sm1, sm0*s.y)); // amp*(m0*V + m1*delta)/N
    }
    __syncthreads();
    #pragma unroll
    for (int g = 0; g < ROWS/4; ++g)
      fft512_inv(&rows[((g<<2)+wid)*512], 1, lane, w512);
    for (int i = t; i < ROWS*512; i += 256) {
      int r = i >> 9, n1 = i & 511;
      int q = q0 + r;
      int k2 = ((q&7)<<6) | (q&56) | (q>>6);
      Xe[(size_t)q*512 + n1] = cmulc(rows[i], wbig[(n1*k2) & (MFT-1)]);
    }
  } else {
    for (int i = t; i < ROWS*512; i += 256) {
      int r = i >> 9, n1 = i & 511;
      Xe[(size_t)(q0 + r)*512 + n1] = rows[i];
    }
  }
}

// -------- FFT pass C: inverse column FFT + dirac shift + output write --------
__global__ __launch_bounds__(256) void k_passC(const float2* __restrict__ Xb,
                                               float* __restrict__ dout,
                                               const float2* __restrict__ wbig,
                                               const int* __restrict__ shiftA,
                                               int e0) {
  __shared__ float2 w512[512];
  __shared__ float2 tile[512*(COLS+1)];
  int t = threadIdx.x;
  for (int i = t; i < 512; i += 256) w512[i] = wbig[(size_t)i*512];
  const float2* Xe = Xb + (size_t)blockIdx.y * MFT;
  int c0 = blockIdx.x * COLS;
  for (int i = t; i < 512*COLS; i += 256) {
    int cc = i & (COLS-1), q = i >> 3;
    tile[q*(COLS+1) + cc] = Xe[c0 + cc + ((size_t)q<<9)];
  }
  __syncthreads();
  int wid = t >> 6, lane = t & 63;
  #pragma unroll
  for (int g = 0; g < COLS/4; ++g)
    fft512_inv(&tile[(g<<2) + wid], COLS+1, lane, w512);
  int n = e0 + blockIdx.y;
  int sh = shiftA[n];
  float* dp = dout + (size_t)n*NSMP;
  for (int i = t; i < 256*COLS; i += 256) {   // only p < NS needed (n2 < 256)
    int cc = i & (COLS-1), n2 = i >> 3;
    int p = c0 + cc + (n2<<9);
    int o = p + sh;
    if (o < NSMP) dp[o] = tile[n2*(COLS+1) + cc].x;
  }
}

} // namespace

extern "C" void kernel_launch(void* const* d_in, const int* in_sizes, int n_in,
                              void* d_out, int out_size, void* d_ws, size_t ws_size,
                              hipStream_t stream) {
  (void)in_sizes; (void)n_in;
  const float* voice  = (const float*)d_in[0];
  const float* cpc    = (const float*)d_in[1];
  const float* amps   = (const float*)d_in[2];
  const float* room   = (const float*)d_in[3];
  const float* rmix   = (const float*)d_in[4];
  const float* times  = (const float*)d_in[5];
  const float* cp_tab = (const float*)d_in[6];
  const float* verbs  = (const float*)d_in[7];
  const float* w_in   = (const float*)d_in[8];
  const float* w_ih   = (const float*)d_in[9];
  const float* w_hh   = (const float*)d_in[10];
  const float* w_out  = (const float*)d_in[11];
  float* out = (float*)d_out;

  char* base = (char*)d_ws;
  size_t off = 0;
  auto carve = [&](size_t bytes) -> void* {
    void* p = base + off;
    off = (off + bytes + 255) & ~(size_t)255;
    return p;
  };
  float*  sig  = (float*) carve((size_t)NEV*NSMP*4);     // 64 MB
  float2* wbig = (float2*)carve((size_t)MFT*8);          // 2 MB
  float2* spec = (float2*)carve((size_t)16*MFT*8);       // 32 MB (verb spectra)
  int*   vidx  = (int*)  carve(NEV*4);
  int*   cpidx = (int*)  carve(NEV*4);
  int*   ridx  = (int*)  carve(NEV*4);
  int*   shf   = (int*)  carve(NEV*4);
  float* m0    = (float*)carve(NEV*4);
  float* m1    = (float*)carve(NEV*4);
  float* amp   = (float*)carve(NEV*4);
  size_t overlay = off;                                   // FFT chunk buffer overlays the buffers below
  float* mred  = (float*)carve((size_t)8*128*16*4);       // dead after k_rnn
  float* ctrl  = (float*)carve((size_t)NEV*2048*4);       // dead after k_rnn
  float* hs    = (float*)carve((size_t)NEV*128*128*4);    // dead after k_gemm
  float2* X = (float2*)(base + overlay);
  size_t rem = (ws_size > overlay) ? (ws_size - overlay) : 0;
  int C = (int)(rem / ((size_t)MFT*8));
  if (C > NEV) C = NEV;
  if (C < 1) C = 1;

  hipMemsetAsync(d_out, 0, (size_t)out_size*sizeof(float), stream);

  k_params<<<NEV, 64, 0, stream>>>(voice, cpc, amps, room, rmix, times,
                                   vidx, cpidx, ridx, shf, m0, m1, amp);
  k_wbig<<<MFT/256, 256, 0, stream>>>(wbig);
  k_mred<<<dim3(128, 8), 64, 0, stream>>>(w_ih, w_in, mred);
  k_topk<<<NEV, 256, 0, stream>>>(cp_tab, cpidx, ctrl);
  k_rnn<<<NEV, 128, 0, stream>>>(ctrl, mred, w_hh, vidx, hs);
  k_gemm<<<dim3(8, NEV), 256, 0, stream>>>(hs, w_out, vidx, sig);

  // verb spectra: identical forward pipeline (pass A + pass B fwd-only), in place in `spec`
  k_passA<<<dim3(64, 16), 256, 0, stream>>>(verbs, spec, wbig);
  k_passB<false><<<dim3(64, 16), 256, 0, stream>>>(spec, nullptr, wbig,
                                                   nullptr, nullptr, nullptr, nullptr, 0);

  for (int e0 = 0; e0 < NEV; e0 += C) {
    int ce = (NEV - e0 < C) ? (NEV - e0) : C;
    k_passA<<<dim3(64, ce), 256, 0, stream>>>(sig + (size_t)e0*NSMP, X, wbig);
    k_passB<true><<<dim3(64, ce), 256, 0, stream>>>(X, spec, wbig, ridx, m0, m1, amp, e0);
    k_passC<<<dim3(64, ce), 256, 0, stream>>>(X, out, wbig, shf, e0);
  }
}